// Round 1
// baseline (997.717 us; speedup 1.0000x reference)
//
#include <hip/hip_runtime.h>
#include <stdint.h>

#define C_IN 128
#define NUMD 524288
#define LNUMD 32768
#define NNUM_DM1 (LNUMD + NUMD/8)
#define PREFIX 16384
#define N_CONV (PREFIX + NNUM_DM1)   // 114688
#define N_EDGES (N_CONV * 7)         // 802816
#define ND8 (NUMD/8)                 // 65536
#define KC 945
#define KCP 960
#define AGG_STRIDE 968

typedef __attribute__((ext_vector_type(8))) short short8;
typedef __attribute__((ext_vector_type(4))) float f32x4;

__device__ inline ushort f2b(float f){
  union { float f; uint32_t u; } v; v.f = f;
  uint32_t r = v.u + 0x7fffu + ((v.u >> 16) & 1u);
  return (ushort)(r >> 16);
}
__device__ inline float b2f_lo(uint32_t u){ union { uint32_t u; float f; } v; v.u = u << 16; return v.f; }
__device__ inline float b2f_hi(uint32_t u){ union { uint32_t u; float f; } v; v.u = u & 0xffff0000u; return v.f; }

// ---- copy prefix + leaf rows into bf16 x_conv ----
__global__ void k_copy(const float* __restrict__ x, ushort* __restrict__ xconv){
  int gid = blockIdx.x*256 + threadIdx.x;          // (PREFIX+LNUMD)*32 threads
  int row = gid >> 5;
  int seg = (gid & 31) * 4;
  int srow, drow;
  if (row < PREFIX){ srow = row; drow = row; }
  else { int k = row - PREFIX; srow = PREFIX + k; drow = PREFIX + 3*k; }
  const float4 f = *(const float4*)(x + (size_t)srow*C_IN + seg);
  ushort4 o; o.x=f2b(f.x); o.y=f2b(f.y); o.z=f2b(f.z); o.w=f2b(f.w);
  *(ushort4*)(xconv + (size_t)drow*C_IN + seg) = o;
}

// ---- convert weights: w_conv -> W^T bf16 [128][960]; w_down -> bf16 [128][1024] ----
__global__ void k_prepw(const float* __restrict__ wconv, const float* __restrict__ wdown,
                        ushort* __restrict__ w16t, ushort* __restrict__ wd16){
  int gid = blockIdx.x*256 + threadIdx.x;
  if (gid < 128*KCP){
    int o = gid / KCP, k = gid - o*KCP;
    float v = (k < KC) ? wconv[(size_t)k*128 + o] : 0.f;
    w16t[gid] = f2b(v);
  } else {
    int i = gid - 128*KCP;
    wd16[i] = f2b(wdown[i]);
  }
}

// ---- CSR build ----
__global__ void k_hist(const int* __restrict__ ei, int* __restrict__ cnt){
  int e = blockIdx.x*256 + threadIdx.x;
  if (e < N_EDGES) atomicAdd(&cnt[ei[e]], 1);
}

__global__ void k_scan(int* __restrict__ cnt, int* __restrict__ row_ptr){
  __shared__ int part[1024];
  const int t = threadIdx.x;
  const int base = t * 112;                       // N_CONV/1024 = 112
  int s = 0;
  for (int i=0;i<112;i++) s += cnt[base+i];
  part[t] = s;
  __syncthreads();
  for (int off=1; off<1024; off<<=1){
    int v = part[t];
    int ad = (t >= off) ? part[t-off] : 0;
    __syncthreads();
    part[t] = v + ad;
    __syncthreads();
  }
  int run = (t==0) ? 0 : part[t-1];
  for (int i=0;i<112;i++){
    int c = cnt[base+i];
    row_ptr[base+i] = run;
    cnt[base+i] = run;                            // becomes cursor
    run += c;
  }
  if (t == 1023) row_ptr[N_CONV] = run;
}

__global__ void k_scatter(const int* __restrict__ ei, const int* __restrict__ et,
                          int* __restrict__ cur, int* __restrict__ rs,
                          int* __restrict__ cs, int* __restrict__ ts){
  int e = blockIdx.x*256 + threadIdx.x;
  if (e >= N_EDGES) return;
  int r = ei[e];
  int pos = atomicAdd(&cur[r], 1);
  rs[pos] = r; cs[pos] = ei[N_EDGES + e]; ts[pos] = et[e];
}

// ---- down-projection GEMM: xd(65536x1024) @ wd^T -> scattered bf16 rows of x_conv ----
__global__ __launch_bounds__(256) void k_down(const float* __restrict__ x, const ushort* __restrict__ wd16,
                                              ushort* __restrict__ xconv){
  __shared__ ushort at[64][56];                   // padded stride vs bank conflicts
  const int tid = threadIdx.x;
  const int n0 = blockIdx.x * 64;
  const float* xd = x + (size_t)(PREFIX+LNUMD)*C_IN;
  const int wid = tid >> 6, l = tid & 63;
  const int arow = l & 15, kgrp = l >> 4;
  f32x4 acc[8];
  #pragma unroll
  for (int s=0;s<8;s++) acc[s] = (f32x4){0.f,0.f,0.f,0.f};
  const int srow = tid >> 2, kseg = (tid & 3) * 8;
  for (int k0 = 0; k0 < 1024; k0 += 32){
    __syncthreads();
    const float* src = xd + (size_t)(n0+srow)*1024 + k0 + kseg;
    float4 f0 = *(const float4*)src;
    float4 f1 = *(const float4*)(src+4);
    uint4 pk;
    pk.x = (uint)f2b(f0.x) | ((uint)f2b(f0.y)<<16);
    pk.y = (uint)f2b(f0.z) | ((uint)f2b(f0.w)<<16);
    pk.z = (uint)f2b(f1.x) | ((uint)f2b(f1.y)<<16);
    pk.w = (uint)f2b(f1.z) | ((uint)f2b(f1.w)<<16);
    *(uint4*)&at[srow][kseg] = pk;
    __syncthreads();
    short8 a = *(const short8*)&at[16*wid + arow][kgrp*8];
    #pragma unroll
    for (int s=0;s<8;s++){
      short8 b = *(const short8*)(wd16 + (size_t)(s*16 + arow)*1024 + k0 + kgrp*8);
      acc[s] = __builtin_amdgcn_mfma_f32_16x16x32_bf16(a, b, acc[s], 0,0,0);
    }
  }
  #pragma unroll
  for (int s=0;s<8;s++){
    int col = s*16 + arow;
    #pragma unroll
    for (int r=0;r<4;r++){
      int n = n0 + 16*wid + kgrp*4 + r;           // C/D: row=(lane>>4)*4+reg
      int i = 3*(n>>1) + 1 + (n&1);               // non-leaf merged index
      xconv[(size_t)(PREFIX + i)*C_IN + col] = f2b(acc[s][r]);
    }
  }
}

// ---- fused per-16-vertex aggregation + GEMM vs W^T ----
__global__ __launch_bounds__(256) void k_conv(const int* __restrict__ row_ptr, const int* __restrict__ rs,
    const int* __restrict__ cs, const int* __restrict__ ts, const ushort* __restrict__ xconv,
    const int* __restrict__ ntype, const ushort* __restrict__ w16t, float* __restrict__ out){
  __shared__ float aggf[8][KCP];
  __shared__ ushort agg16[16][AGG_STRIDE];
  const int tid = threadIdx.x;
  const int vbase = blockIdx.x * 16;
  const int slot = tid >> 4, lane16 = tid & 15;
  for (int p = 0; p < 2; p++){
    for (int i = tid; i < 8*KCP; i += 256) ((float*)aggf)[i] = 0.f;
    __syncthreads();
    const int gv0 = vbase + p*8;
    const int e0 = row_ptr[gv0], e1 = row_ptr[gv0 + 8];
    for (int e = e0 + slot; e < e1; e += 16){
      int r = rs[e], c = cs[e], t = ts[e];
      int lv = r - gv0;
      uint4 d = *(const uint4*)(xconv + (size_t)c*C_IN + lane16*8);
      float* dst = &aggf[lv][t*135 + lane16*8];
      atomicAdd(dst+0, b2f_lo(d.x)); atomicAdd(dst+1, b2f_hi(d.x));
      atomicAdd(dst+2, b2f_lo(d.y)); atomicAdd(dst+3, b2f_hi(d.y));
      atomicAdd(dst+4, b2f_lo(d.z)); atomicAdd(dst+5, b2f_hi(d.z));
      atomicAdd(dst+6, b2f_lo(d.w)); atomicAdd(dst+7, b2f_hi(d.w));
      if (lane16 == 0) atomicAdd(&aggf[lv][t*135 + 128 + ntype[c]], 1.f);
    }
    __syncthreads();
    for (int i = tid; i < 8*KCP; i += 256){
      int lv = i / KCP, k = i - lv*KCP;
      agg16[p*8 + lv][k] = f2b(aggf[lv][k]);
    }
    __syncthreads();
  }
  // GEMM: (16 x 960) @ (960 x 128)
  const int wid = tid >> 6, l = tid & 63;
  const int arow = l & 15, kgrp = l >> 4;
  const int cb0 = wid * 32;
  f32x4 acc0 = {0.f,0.f,0.f,0.f}, acc1 = {0.f,0.f,0.f,0.f};
  for (int k0 = 0; k0 < KCP; k0 += 32){
    short8 a  = *(const short8*)&agg16[arow][k0 + kgrp*8];
    short8 b0 = *(const short8*)(w16t + (size_t)(cb0 + arow)*KCP + k0 + kgrp*8);
    short8 b1 = *(const short8*)(w16t + (size_t)(cb0 + 16 + arow)*KCP + k0 + kgrp*8);
    acc0 = __builtin_amdgcn_mfma_f32_16x16x32_bf16(a, b0, acc0, 0,0,0);
    acc1 = __builtin_amdgcn_mfma_f32_16x16x32_bf16(a, b1, acc1, 0,0,0);
  }
  #pragma unroll
  for (int r = 0; r < 4; r++){
    size_t ro = (size_t)(vbase + kgrp*4 + r) * C_IN;
    out[ro + cb0 + arow] = acc0[r];
    out[ro + cb0 + 16 + arow] = acc1[r];
  }
}

extern "C" void kernel_launch(void* const* d_in, const int* in_sizes, int n_in,
                              void* d_out, int out_size, void* d_ws, size_t ws_size,
                              hipStream_t stream){
  const float* x     = (const float*)d_in[0];
  const int*   ei    = (const int*)d_in[2];
  const int*   et    = (const int*)d_in[3];
  const int*   nt    = (const int*)d_in[4];
  const float* wdown = (const float*)d_in[5];
  const float* wconv = (const float*)d_in[6];
  float* out = (float*)d_out;

  char* p = (char*)d_ws;
  ushort* xconv = (ushort*)p; p += (size_t)N_CONV*C_IN*2;
  ushort* w16t  = (ushort*)p; p += (size_t)128*KCP*2;
  ushort* wd16  = (ushort*)p; p += (size_t)128*1024*2;
  int* cnt      = (int*)p;    p += (size_t)N_CONV*4;
  int* row_ptr  = (int*)p;    p += (size_t)(N_CONV+64)*4;
  int* rs       = (int*)p;    p += (size_t)N_EDGES*4;
  int* cs       = (int*)p;    p += (size_t)N_EDGES*4;
  int* ts       = (int*)p;    p += (size_t)N_EDGES*4;

  hipMemsetAsync(cnt, 0, (size_t)N_CONV*4, stream);
  k_hist<<<N_EDGES/256, 256, 0, stream>>>(ei, cnt);
  k_scan<<<1, 1024, 0, stream>>>(cnt, row_ptr);
  k_scatter<<<N_EDGES/256, 256, 0, stream>>>(ei, et, cnt, rs, cs, ts);
  k_copy<<<(PREFIX+LNUMD)*32/256, 256, 0, stream>>>(x, xconv);
  k_prepw<<<(128*KCP + 128*1024)/256, 256, 0, stream>>>(wconv, wdown, w16t, wd16);
  k_down<<<ND8/64, 256, 0, stream>>>(x, wd16, xconv);
  k_conv<<<N_CONV/16, 256, 0, stream>>>(row_ptr, rs, cs, ts, xconv, nt, w16t, out);
}

// Round 2
// 572.497 us; speedup vs baseline: 1.7427x; 1.7427x over previous
//
#include <hip/hip_runtime.h>
#include <stdint.h>

#define C_IN 128
#define NUMD 524288
#define LNUMD 32768
#define NNUM_DM1 (LNUMD + NUMD/8)
#define PREFIX 16384
#define N_CONV (PREFIX + NNUM_DM1)   // 114688
#define N_EDGES (N_CONV * 7)         // 802816
#define ND8 (NUMD/8)                 // 65536
#define KC 945
#define KCP 960
#define AGG_STRIDE 968

typedef __attribute__((ext_vector_type(8))) short short8;
typedef __attribute__((ext_vector_type(4))) float f32x4;

__device__ inline ushort f2b(float f){
  union { float f; uint32_t u; } v; v.f = f;
  uint32_t r = v.u + 0x7fffu + ((v.u >> 16) & 1u);
  return (ushort)(r >> 16);
}
__device__ inline float b2f_lo(uint32_t u){ union { uint32_t u; float f; } v; v.u = u << 16; return v.f; }
__device__ inline float b2f_hi(uint32_t u){ union { uint32_t u; float f; } v; v.u = u & 0xffff0000u; return v.f; }

// ---- copy prefix + leaf rows into bf16 x_conv ----
__global__ void k_copy(const float* __restrict__ x, ushort* __restrict__ xconv){
  int gid = blockIdx.x*256 + threadIdx.x;          // (PREFIX+LNUMD)*32 threads
  int row = gid >> 5;
  int seg = (gid & 31) * 4;
  int srow, drow;
  if (row < PREFIX){ srow = row; drow = row; }
  else { int k = row - PREFIX; srow = PREFIX + k; drow = PREFIX + 3*k; }
  const float4 f = *(const float4*)(x + (size_t)srow*C_IN + seg);
  ushort4 o; o.x=f2b(f.x); o.y=f2b(f.y); o.z=f2b(f.z); o.w=f2b(f.w);
  *(ushort4*)(xconv + (size_t)drow*C_IN + seg) = o;
}

// ---- convert weights: w_conv -> W^T bf16 [128][960]; w_down -> bf16 [128][1024] ----
__global__ void k_prepw(const float* __restrict__ wconv, const float* __restrict__ wdown,
                        ushort* __restrict__ w16t, ushort* __restrict__ wd16){
  int gid = blockIdx.x*256 + threadIdx.x;
  if (gid < 128*KCP){
    int o = gid / KCP, k = gid - o*KCP;
    float v = (k < KC) ? wconv[(size_t)k*128 + o] : 0.f;
    w16t[gid] = f2b(v);
  } else {
    int i = gid - 128*KCP;
    wd16[i] = f2b(wdown[i]);
  }
}

// ---- CSR build ----
__global__ void k_hist(const int* __restrict__ ei, int* __restrict__ cnt){
  int e = blockIdx.x*256 + threadIdx.x;
  if (e < N_EDGES) atomicAdd(&cnt[ei[e]], 1);
}

__global__ void k_scan(int* __restrict__ cnt, int* __restrict__ row_ptr){
  __shared__ int part[1024];
  const int t = threadIdx.x;
  const int base = t * 112;                       // N_CONV/1024 = 112
  int s = 0;
  for (int i=0;i<112;i++) s += cnt[base+i];
  part[t] = s;
  __syncthreads();
  for (int off=1; off<1024; off<<=1){
    int v = part[t];
    int ad = (t >= off) ? part[t-off] : 0;
    __syncthreads();
    part[t] = v + ad;
    __syncthreads();
  }
  int run = (t==0) ? 0 : part[t-1];
  for (int i=0;i<112;i++){
    int c = cnt[base+i];
    row_ptr[base+i] = run;
    cnt[base+i] = run;                            // becomes cursor
    run += c;
  }
  if (t == 1023) row_ptr[N_CONV] = run;
}

__global__ void k_scatter(const int* __restrict__ ei, const int* __restrict__ et,
                          int* __restrict__ cur, int* __restrict__ cs, int* __restrict__ ts){
  int e = blockIdx.x*256 + threadIdx.x;
  if (e >= N_EDGES) return;
  int r = ei[e];
  int pos = atomicAdd(&cur[r], 1);
  cs[pos] = ei[N_EDGES + e]; ts[pos] = et[e];
}

// ---- down-projection GEMM: xd(65536x1024) @ wd^T -> scattered bf16 rows of x_conv ----
__global__ __launch_bounds__(256) void k_down(const float* __restrict__ x, const ushort* __restrict__ wd16,
                                              ushort* __restrict__ xconv){
  __shared__ ushort at[64][56];                   // padded stride vs bank conflicts
  const int tid = threadIdx.x;
  const int n0 = blockIdx.x * 64;
  const float* xd = x + (size_t)(PREFIX+LNUMD)*C_IN;
  const int wid = tid >> 6, l = tid & 63;
  const int arow = l & 15, kgrp = l >> 4;
  f32x4 acc[8];
  #pragma unroll
  for (int s=0;s<8;s++) acc[s] = (f32x4){0.f,0.f,0.f,0.f};
  const int srow = tid >> 2, kseg = (tid & 3) * 8;
  for (int k0 = 0; k0 < 1024; k0 += 32){
    __syncthreads();
    const float* src = xd + (size_t)(n0+srow)*1024 + k0 + kseg;
    float4 f0 = *(const float4*)src;
    float4 f1 = *(const float4*)(src+4);
    uint4 pk;
    pk.x = (uint)f2b(f0.x) | ((uint)f2b(f0.y)<<16);
    pk.y = (uint)f2b(f0.z) | ((uint)f2b(f0.w)<<16);
    pk.z = (uint)f2b(f1.x) | ((uint)f2b(f1.y)<<16);
    pk.w = (uint)f2b(f1.z) | ((uint)f2b(f1.w)<<16);
    *(uint4*)&at[srow][kseg] = pk;
    __syncthreads();
    short8 a = *(const short8*)&at[16*wid + arow][kgrp*8];
    #pragma unroll
    for (int s=0;s<8;s++){
      short8 b = *(const short8*)(wd16 + (size_t)(s*16 + arow)*1024 + k0 + kgrp*8);
      acc[s] = __builtin_amdgcn_mfma_f32_16x16x32_bf16(a, b, acc[s], 0,0,0);
    }
  }
  #pragma unroll
  for (int s=0;s<8;s++){
    int col = s*16 + arow;
    #pragma unroll
    for (int r=0;r<4;r++){
      int n = n0 + 16*wid + kgrp*4 + r;           // C/D: row=(lane>>4)*4+reg
      int i = 3*(n>>1) + 1 + (n&1);               // non-leaf merged index
      xconv[(size_t)(PREFIX + i)*C_IN + col] = f2b(acc[s][r]);
    }
  }
}

// ---- fused per-vertex aggregation (register acc, no atomics) + GEMM vs W^T ----
__global__ __launch_bounds__(256, 4) void k_conv(const int* __restrict__ row_ptr,
    const int* __restrict__ cs, const int* __restrict__ ts, const ushort* __restrict__ xconv,
    const int* __restrict__ ntype, const ushort* __restrict__ w16t, float* __restrict__ out){
  __shared__ ushort agg16[16][AGG_STRIDE];
  __shared__ float cntf[16][56];
  const int tid = threadIdx.x;
  const int vbase = blockIdx.x * 16;
  const int slot = tid >> 4, lane16 = tid & 15;

  for (int i = tid; i < 16*56; i += 256) ((float*)cntf)[i] = 0.f;
  __syncthreads();

  float a0[8], a1[8], a2[8], a3[8], a4[8], a5[8], a6[8];
  #pragma unroll
  for (int j=0;j<8;j++){ a0[j]=0.f;a1[j]=0.f;a2[j]=0.f;a3[j]=0.f;a4[j]=0.f;a5[j]=0.f;a6[j]=0.f; }

  const int v = vbase + slot;
  const int e0 = row_ptr[v], e1 = row_ptr[v+1];
  for (int e = e0; e < e1; ++e){
    const int c = cs[e], t = ts[e];
    uint4 d = *(const uint4*)(xconv + (size_t)c*C_IN + lane16*8);
    float f[8];
    f[0]=b2f_lo(d.x); f[1]=b2f_hi(d.x);
    f[2]=b2f_lo(d.y); f[3]=b2f_hi(d.y);
    f[4]=b2f_lo(d.z); f[5]=b2f_hi(d.z);
    f[6]=b2f_lo(d.w); f[7]=b2f_hi(d.w);
    #define ADDC(A) { _Pragma("unroll") for(int j=0;j<8;j++) A[j]+=f[j]; }
    switch(t){
      case 0: ADDC(a0); break;
      case 1: ADDC(a1); break;
      case 2: ADDC(a2); break;
      case 3: ADDC(a3); break;
      case 4: ADDC(a4); break;
      case 5: ADDC(a5); break;
      default: ADDC(a6); break;
    }
    #undef ADDC
    if (lane16 == 0){
      int nt_ = ntype[c];
      cntf[slot][t*7 + nt_] += 1.f;
    }
  }

  // dump register accumulators -> bf16 LDS row for this vertex
  #define DUMP(A,T) { _Pragma("unroll") for(int j=0;j<8;j++) \
      agg16[slot][T*135 + lane16*8 + j] = f2b(A[j]); }
  DUMP(a0,0) DUMP(a1,1) DUMP(a2,2) DUMP(a3,3) DUMP(a4,4) DUMP(a5,5) DUMP(a6,6)
  #undef DUMP
  // one-hot counts: lane t (<7) writes the 7 node-type counts for type t
  if (lane16 < 7){
    #pragma unroll
    for (int j=0;j<7;j++)
      agg16[slot][lane16*135 + 128 + j] = f2b(cntf[slot][lane16*7 + j]);
  }
  // zero K padding [945, 961)
  { int r = tid >> 4, k = 945 + (tid & 15); agg16[r][k] = 0; }
  __syncthreads();

  // GEMM: (16 x 960) @ (960 x 128)
  const int wid = tid >> 6, l = tid & 63;
  const int arow = l & 15, kgrp = l >> 4;
  const int cb0 = wid * 32;
  f32x4 acc0 = {0.f,0.f,0.f,0.f}, acc1 = {0.f,0.f,0.f,0.f};
  for (int k0 = 0; k0 < KCP; k0 += 32){
    short8 a  = *(const short8*)&agg16[arow][k0 + kgrp*8];
    short8 b0 = *(const short8*)(w16t + (size_t)(cb0 + arow)*KCP + k0 + kgrp*8);
    short8 b1 = *(const short8*)(w16t + (size_t)(cb0 + 16 + arow)*KCP + k0 + kgrp*8);
    acc0 = __builtin_amdgcn_mfma_f32_16x16x32_bf16(a, b0, acc0, 0,0,0);
    acc1 = __builtin_amdgcn_mfma_f32_16x16x32_bf16(a, b1, acc1, 0,0,0);
  }
  #pragma unroll
  for (int r = 0; r < 4; r++){
    size_t ro = (size_t)(vbase + kgrp*4 + r) * C_IN;
    out[ro + cb0 + arow] = acc0[r];
    out[ro + cb0 + 16 + arow] = acc1[r];
  }
}

extern "C" void kernel_launch(void* const* d_in, const int* in_sizes, int n_in,
                              void* d_out, int out_size, void* d_ws, size_t ws_size,
                              hipStream_t stream){
  const float* x     = (const float*)d_in[0];
  const int*   ei    = (const int*)d_in[2];
  const int*   et    = (const int*)d_in[3];
  const int*   nt    = (const int*)d_in[4];
  const float* wdown = (const float*)d_in[5];
  const float* wconv = (const float*)d_in[6];
  float* out = (float*)d_out;

  char* p = (char*)d_ws;
  ushort* xconv = (ushort*)p; p += (size_t)N_CONV*C_IN*2;
  ushort* w16t  = (ushort*)p; p += (size_t)128*KCP*2;
  ushort* wd16  = (ushort*)p; p += (size_t)128*1024*2;
  int* cnt      = (int*)p;    p += (size_t)N_CONV*4;
  int* row_ptr  = (int*)p;    p += (size_t)(N_CONV+64)*4;
  int* cs       = (int*)p;    p += (size_t)N_EDGES*4;
  int* ts       = (int*)p;    p += (size_t)N_EDGES*4;

  hipMemsetAsync(cnt, 0, (size_t)N_CONV*4, stream);
  k_hist<<<N_EDGES/256, 256, 0, stream>>>(ei, cnt);
  k_scan<<<1, 1024, 0, stream>>>(cnt, row_ptr);
  k_scatter<<<N_EDGES/256, 256, 0, stream>>>(ei, et, cnt, cs, ts);
  k_copy<<<(PREFIX+LNUMD)*32/256, 256, 0, stream>>>(x, xconv);
  k_prepw<<<(128*KCP + 128*1024)/256, 256, 0, stream>>>(wconv, wdown, w16t, wd16);
  k_down<<<ND8/64, 256, 0, stream>>>(x, wd16, xconv);
  k_conv<<<N_CONV/16, 256, 0, stream>>>(row_ptr, cs, ts, xconv, nt, w16t, out);
}

// Round 3
// 483.100 us; speedup vs baseline: 2.0652x; 1.1850x over previous
//
#include <hip/hip_runtime.h>
#include <stdint.h>

#define C_IN 128
#define NUMD 524288
#define LNUMD 32768
#define NNUM_DM1 (LNUMD + NUMD/8)
#define PREFIX 16384
#define N_CONV (PREFIX + NNUM_DM1)   // 114688
#define N_EDGES (N_CONV * 7)         // 802816
#define ND8 (NUMD/8)                 // 65536
#define KC 945
#define KCP 960
#define AGG_STRIDE 968

#define HIST_BLK (N_EDGES/256)               // 3136
#define COPY_BLK ((PREFIX+LNUMD)*32/256)     // 6144
#define PREPW_BLK ((128*KCP + 128*1024)/256) // 992
#define SCAT_BLK (N_EDGES/256)               // 3136
#define DOWN_BLK (ND8/64)                    // 1024

typedef __attribute__((ext_vector_type(8))) short short8;
typedef __attribute__((ext_vector_type(4))) float f32x4;

__device__ inline ushort f2b(float f){
  union { float f; uint32_t u; } v; v.f = f;
  uint32_t r = v.u + 0x7fffu + ((v.u >> 16) & 1u);
  return (ushort)(r >> 16);
}
__device__ inline float b2f_lo(uint32_t u){ union { uint32_t u; float f; } v; v.u = u << 16; return v.f; }
__device__ inline float b2f_hi(uint32_t u){ union { uint32_t u; float f; } v; v.u = u & 0xffff0000u; return v.f; }

// ---- fused: hist | copy prefix+leaf rows | weight conversion ----
__global__ void k_prep(const float* __restrict__ x, const float* __restrict__ wconv,
                       const float* __restrict__ wdown, const int* __restrict__ ei,
                       ushort* __restrict__ xconv, ushort* __restrict__ w16t,
                       ushort* __restrict__ wd16, int* __restrict__ cnt){
  const int bid = blockIdx.x;
  if (bid < HIST_BLK){
    int e = bid*256 + threadIdx.x;
    atomicAdd(&cnt[ei[e]], 1);
  } else if (bid < HIST_BLK + COPY_BLK){
    int gid = (bid - HIST_BLK)*256 + threadIdx.x;
    int row = gid >> 5, seg = (gid & 31) * 4;
    int srow, drow;
    if (row < PREFIX){ srow = row; drow = row; }
    else { int k = row - PREFIX; srow = PREFIX + k; drow = PREFIX + 3*k; }
    const float4 f = *(const float4*)(x + (size_t)srow*C_IN + seg);
    ushort4 o; o.x=f2b(f.x); o.y=f2b(f.y); o.z=f2b(f.z); o.w=f2b(f.w);
    *(ushort4*)(xconv + (size_t)drow*C_IN + seg) = o;
  } else {
    int gid = (bid - HIST_BLK - COPY_BLK)*256 + threadIdx.x;
    if (gid < 128*KCP){
      int o = gid / KCP, k = gid - o*KCP;
      float v = (k < KC) ? wconv[(size_t)k*128 + o] : 0.f;
      w16t[gid] = f2b(v);
    } else {
      int i = gid - 128*KCP;
      wd16[i] = f2b(wdown[i]);
    }
  }
}

// ---- 3-stage coalesced scan of cnt[N_CONV] -> row_ptr + cursor ----
__global__ void k_scanA(const int* __restrict__ cnt, int* __restrict__ bsum){
  __shared__ int r[256];
  const int t = threadIdx.x, base = blockIdx.x*1024;
  int s = cnt[base+t] + cnt[base+t+256] + cnt[base+t+512] + cnt[base+t+768];
  r[t] = s; __syncthreads();
  for (int off=128; off>0; off>>=1){ if (t<off) r[t]+=r[t+off]; __syncthreads(); }
  if (t==0) bsum[blockIdx.x] = r[0];
}

__global__ void k_scanB(int* __restrict__ bsum){
  __shared__ int ps[128];
  const int t = threadIdx.x;
  int v = (t < 112) ? bsum[t] : 0;
  ps[t] = v; __syncthreads();
  for (int off=1; off<128; off<<=1){
    int val = ps[t];
    int add = (t>=off) ? ps[t-off] : 0;
    __syncthreads();
    ps[t] = val + add;
    __syncthreads();
  }
  int excl = (t==0) ? 0 : ps[t-1];
  if (t < 112) bsum[t] = excl;
}

__global__ void k_scanC(int* __restrict__ cnt, const int* __restrict__ bsum,
                        int* __restrict__ row_ptr){
  __shared__ int ps[256];
  const int b = blockIdx.x, t = threadIdx.x;
  int4 v = *(const int4*)(cnt + b*1024 + t*4);
  int s0 = v.x, s1 = s0+v.y, s2 = s1+v.z, s3 = s2+v.w;
  ps[t] = s3; __syncthreads();
  for (int off=1; off<256; off<<=1){
    int val = ps[t];
    int add = (t>=off) ? ps[t-off] : 0;
    __syncthreads();
    ps[t] = val + add;
    __syncthreads();
  }
  int excl = ((t==0) ? 0 : ps[t-1]) + bsum[b];
  int4 rp; rp.x = excl; rp.y = excl+s0; rp.z = excl+s1; rp.w = excl+s2;
  *(int4*)(row_ptr + b*1024 + t*4) = rp;
  *(int4*)(cnt + b*1024 + t*4) = rp;            // becomes cursor
  if (b == 111 && t == 255) row_ptr[N_CONV] = excl + s3;
}

// ---- fused: edge scatter (packed col|type|ntype) | down-projection GEMM ----
__global__ __launch_bounds__(256) void k_sd(const int* __restrict__ ei, const int* __restrict__ et,
    const int* __restrict__ ntype, int* __restrict__ cur, int* __restrict__ csp,
    const float* __restrict__ x, const ushort* __restrict__ wd16, ushort* __restrict__ xconv){
  const int bid = blockIdx.x;
  if (bid < SCAT_BLK){
    int e = bid*256 + threadIdx.x;
    int r = ei[e], c = ei[N_EDGES + e], t = et[e];
    int nt_ = ntype[c];
    int pos = atomicAdd(&cur[r], 1);
    csp[pos] = c | (t << 17) | (nt_ << 20);
    return;
  }
  __shared__ ushort at[64][56];
  const int tid = threadIdx.x;
  const int n0 = (bid - SCAT_BLK) * 64;
  const float* xd = x + (size_t)(PREFIX+LNUMD)*C_IN;
  const int wid = tid >> 6, l = tid & 63;
  const int arow = l & 15, kgrp = l >> 4;
  f32x4 acc[8];
  #pragma unroll
  for (int s=0;s<8;s++) acc[s] = (f32x4){0.f,0.f,0.f,0.f};
  const int srow = tid >> 2, kseg = (tid & 3) * 8;
  for (int k0 = 0; k0 < 1024; k0 += 32){
    __syncthreads();
    const float* src = xd + (size_t)(n0+srow)*1024 + k0 + kseg;
    float4 f0 = *(const float4*)src;
    float4 f1 = *(const float4*)(src+4);
    uint4 pk;
    pk.x = (uint)f2b(f0.x) | ((uint)f2b(f0.y)<<16);
    pk.y = (uint)f2b(f0.z) | ((uint)f2b(f0.w)<<16);
    pk.z = (uint)f2b(f1.x) | ((uint)f2b(f1.y)<<16);
    pk.w = (uint)f2b(f1.z) | ((uint)f2b(f1.w)<<16);
    *(uint4*)&at[srow][kseg] = pk;
    __syncthreads();
    short8 a = *(const short8*)&at[16*wid + arow][kgrp*8];
    #pragma unroll
    for (int s=0;s<8;s++){
      short8 b = *(const short8*)(wd16 + (size_t)(s*16 + arow)*1024 + k0 + kgrp*8);
      acc[s] = __builtin_amdgcn_mfma_f32_16x16x32_bf16(a, b, acc[s], 0,0,0);
    }
  }
  #pragma unroll
  for (int s=0;s<8;s++){
    int col = s*16 + arow;
    #pragma unroll
    for (int r=0;r<4;r++){
      int n = n0 + 16*wid + kgrp*4 + r;
      int i = 3*(n>>1) + 1 + (n&1);
      xconv[(size_t)(PREFIX + i)*C_IN + col] = f2b(acc[s][r]);
    }
  }
}

// ---- fused per-vertex aggregation (batch-8 MLP, register acc) + GEMM vs W^T ----
__global__ __launch_bounds__(512, 4) void k_conv(const int* __restrict__ row_ptr,
    const int* __restrict__ csp, const ushort* __restrict__ xconv,
    const ushort* __restrict__ w16t, float* __restrict__ out){
  __shared__ ushort agg16[32][AGG_STRIDE];
  const int tid = threadIdx.x;
  const int vbase = blockIdx.x * 32;
  const int slot = tid >> 4, lane16 = tid & 15;

  float a0[8], a1[8], a2[8], a3[8], a4[8], a5[8], a6[8];
  #pragma unroll
  for (int j=0;j<8;j++){ a0[j]=0.f;a1[j]=0.f;a2[j]=0.f;a3[j]=0.f;a4[j]=0.f;a5[j]=0.f;a6[j]=0.f; }
  float c0=0.f, c1=0.f, c2=0.f, c3=0.f;

  const int v = vbase + slot;
  const int e0 = row_ptr[v], e1 = row_ptr[v+1];
  for (int base = e0; base < e1; base += 8){
    const int n = e1 - base;
    uint4 d[8]; int meta[8];
    #pragma unroll
    for (int i=0;i<8;i++){
      if (i < n){
        int cp = csp[base+i];
        meta[i] = cp;
        d[i] = *(const uint4*)(xconv + (size_t)(cp & 0x1FFFF)*C_IN + lane16*8);
      }
    }
    #pragma unroll
    for (int i=0;i<8;i++){
      if (i < n){
        float f[8];
        f[0]=b2f_lo(d[i].x); f[1]=b2f_hi(d[i].x);
        f[2]=b2f_lo(d[i].y); f[3]=b2f_hi(d[i].y);
        f[4]=b2f_lo(d[i].z); f[5]=b2f_hi(d[i].z);
        f[6]=b2f_lo(d[i].w); f[7]=b2f_hi(d[i].w);
        int t = (meta[i] >> 17) & 7, nt_ = (meta[i] >> 20) & 7;
        #define ADDC(A) { _Pragma("unroll") for(int j=0;j<8;j++) A[j]+=f[j]; }
        switch(t){
          case 0: ADDC(a0); break;
          case 1: ADDC(a1); break;
          case 2: ADDC(a2); break;
          case 3: ADDC(a3); break;
          case 4: ADDC(a4); break;
          case 5: ADDC(a5); break;
          default: ADDC(a6); break;
        }
        #undef ADDC
        int combo = t*7 + nt_;
        c0 += (combo == lane16     ) ? 1.f : 0.f;
        c1 += (combo == lane16 + 16) ? 1.f : 0.f;
        c2 += (combo == lane16 + 32) ? 1.f : 0.f;
        c3 += (combo == lane16 + 48) ? 1.f : 0.f;
      }
    }
  }

  #define DUMP(A,T) { _Pragma("unroll") for(int j=0;j<8;j++) \
      agg16[slot][T*135 + lane16*8 + j] = f2b(A[j]); }
  DUMP(a0,0) DUMP(a1,1) DUMP(a2,2) DUMP(a3,3) DUMP(a4,4) DUMP(a5,5) DUMP(a6,6)
  #undef DUMP
  {
    int q = lane16;      agg16[slot][(q/7)*135 + 128 + (q%7)] = f2b(c0);
    q = lane16 + 16;     agg16[slot][(q/7)*135 + 128 + (q%7)] = f2b(c1);
    q = lane16 + 32;     agg16[slot][(q/7)*135 + 128 + (q%7)] = f2b(c2);
    if (lane16 == 0)     agg16[slot][(48/7)*135 + 128 + (48%7)] = f2b(c3);
  }
  if (lane16 < 15) agg16[slot][945 + lane16] = 0;   // zero K padding [945,960)
  __syncthreads();

  // GEMM: (32 x 960) @ (960 x 128), 8 waves = 2 row-groups x 4 col-groups
  const int w = tid >> 6, l = tid & 63;
  const int arow = l & 15, kgrp = l >> 4;
  const int rg = w >> 2, cg = w & 3;
  const int cb0 = cg * 32;
  f32x4 acc0 = {0.f,0.f,0.f,0.f}, acc1 = {0.f,0.f,0.f,0.f};
  for (int k0 = 0; k0 < KCP; k0 += 32){
    short8 a  = *(const short8*)&agg16[rg*16 + arow][k0 + kgrp*8];
    short8 b0 = *(const short8*)(w16t + (size_t)(cb0 + arow)*KCP + k0 + kgrp*8);
    short8 b1 = *(const short8*)(w16t + (size_t)(cb0 + 16 + arow)*KCP + k0 + kgrp*8);
    acc0 = __builtin_amdgcn_mfma_f32_16x16x32_bf16(a, b0, acc0, 0,0,0);
    acc1 = __builtin_amdgcn_mfma_f32_16x16x32_bf16(a, b1, acc1, 0,0,0);
  }
  #pragma unroll
  for (int r = 0; r < 4; r++){
    size_t ro = (size_t)(vbase + rg*16 + kgrp*4 + r) * C_IN;
    out[ro + cb0 + arow] = acc0[r];
    out[ro + cb0 + 16 + arow] = acc1[r];
  }
}

extern "C" void kernel_launch(void* const* d_in, const int* in_sizes, int n_in,
                              void* d_out, int out_size, void* d_ws, size_t ws_size,
                              hipStream_t stream){
  const float* x     = (const float*)d_in[0];
  const int*   ei    = (const int*)d_in[2];
  const int*   et    = (const int*)d_in[3];
  const int*   nt    = (const int*)d_in[4];
  const float* wdown = (const float*)d_in[5];
  const float* wconv = (const float*)d_in[6];
  float* out = (float*)d_out;

  char* p = (char*)d_ws;
  ushort* xconv = (ushort*)p; p += (size_t)N_CONV*C_IN*2;
  ushort* w16t  = (ushort*)p; p += (size_t)128*KCP*2;
  ushort* wd16  = (ushort*)p; p += (size_t)128*1024*2;
  int* cnt      = (int*)p;    p += (size_t)N_CONV*4;
  int* row_ptr  = (int*)p;    p += (size_t)(N_CONV+64)*4;
  int* bsum     = (int*)p;    p += 512;
  int* csp      = (int*)p;    p += (size_t)N_EDGES*4;

  hipMemsetAsync(cnt, 0, (size_t)N_CONV*4, stream);
  k_prep<<<HIST_BLK + COPY_BLK + PREPW_BLK, 256, 0, stream>>>(x, wconv, wdown, ei, xconv, w16t, wd16, cnt);
  k_scanA<<<112, 256, 0, stream>>>(cnt, bsum);
  k_scanB<<<1, 128, 0, stream>>>(bsum);
  k_scanC<<<112, 256, 0, stream>>>(cnt, bsum, row_ptr);
  k_sd<<<SCAT_BLK + DOWN_BLK, 256, 0, stream>>>(ei, et, nt, cnt, csp, x, wd16, xconv);
  k_conv<<<N_CONV/32, 512, 0, stream>>>(row_ptr, csp, xconv, w16t, out);
}